// Round 1
// baseline (1277.674 us; speedup 1.0000x reference)
//
#include <hip/hip_runtime.h>

// Problem: B=8, S=2048, D_IN=4096, D_OUT=4096, R=16
//   out[m,n] = (s[n]-1)*base[m,n] + s[n]*osora[m,n]
//   base  = x @ W^T  (M=16384,N=4096,K=4096)  -- bf16 MFMA
//   osora = (x@V^T * S) @ U^T * O = t @ W2^T,  W2[n,r]=O[n]S[r]U[n,r]
//   s[n]  = magnitude[n] / ||W[n,:] + W2[n,:]@V||   (fp32)
// Workspace layout (needs ~161 MB):
//   xb 128MB | wb 32MB | vb 128KB | tb 512KB | w2b 128KB | s 16KB | sm1 16KB

#define M_TOT 16384
#define N_TOT 4096
#define K_TOT 4096

typedef __attribute__((ext_vector_type(8))) short bf16x8;
typedef __attribute__((ext_vector_type(4))) float f32x4;

__device__ __forceinline__ unsigned short f2bf(float f){
  union { float f; unsigned int u; } v; v.f = f;
  unsigned int u = v.u;
  u += 0x7FFFu + ((u >> 16) & 1u);   // round-to-nearest-even
  return (unsigned short)(u >> 16);
}

__device__ __forceinline__ void async_lds16(const void* g, void* l){
  __builtin_amdgcn_global_load_lds(
      (const __attribute__((address_space(1))) unsigned int*)g,
      (__attribute__((address_space(3))) unsigned int*)l, 16, 0, 0);
}

// ---------------- cast fp32 -> bf16, 4 elems/thread ----------------
__global__ __launch_bounds__(256) void cast_f32_to_bf16_x4(
    const float* __restrict__ src, unsigned short* __restrict__ dst, int n4){
  int i = blockIdx.x * 256 + threadIdx.x;
  if (i >= n4) return;
  float4 v = ((const float4*)src)[i];
  ushort4 o;
  o.x = f2bf(v.x); o.y = f2bf(v.y); o.z = f2bf(v.z); o.w = f2bf(v.w);
  ((ushort4*)dst)[i] = o;
}

// ---------------- t = x @ V^T  -> bf16 [M][16] ----------------
__global__ __launch_bounds__(256) void tgemm_kernel(
    const unsigned short* __restrict__ xb, const unsigned short* __restrict__ vb,
    unsigned short* __restrict__ tb){
  int lane = threadIdx.x & 63;
  int wave = threadIdx.x >> 6;
  int quad = lane >> 4;
  int r16  = lane & 15;
  int m0 = (blockIdx.x * 4 + wave) * 16;
  const unsigned short* xptr = xb + (m0 + r16) * K_TOT + quad * 8;
  const unsigned short* vptr = vb + r16 * K_TOT + quad * 8;   // V row = rank index
  f32x4 acc = {0.f, 0.f, 0.f, 0.f};
  for (int k = 0; k < K_TOT; k += 32){
    bf16x8 a = *(const bf16x8*)(xptr + k);
    bf16x8 b = *(const bf16x8*)(vptr + k);
    acc = __builtin_amdgcn_mfma_f32_16x16x32_bf16(a, b, acc, 0, 0, 0);
  }
  // C/D: row(m) = quad*4+reg, col(r) = lane&15
  for (int reg = 0; reg < 4; reg++){
    int m = m0 + quad * 4 + reg;
    tb[m * 16 + r16] = f2bf(acc[reg]);
  }
}

// -------- weight_norm -> s, s-1, W2(bf16); 8 rows/block, V chunked in LDS --------
__global__ __launch_bounds__(256) void norm_kernel(
    const float* __restrict__ bw, const float* __restrict__ U,
    const float* __restrict__ S, const float* __restrict__ O,
    const float* __restrict__ mag, const float* __restrict__ V,
    float* __restrict__ s_out, float* __restrict__ sm1_out,
    unsigned short* __restrict__ w2b){
  __shared__ float Vl[16 * 1024];
  __shared__ float C8[8 * 16];
  __shared__ float red[8 * 4];
  int t = threadIdx.x;
  int lane = t & 63, wave = t >> 6;
  int n0 = blockIdx.x * 8;
  if (t < 128){
    int row = t >> 4, r = t & 15;
    int n = n0 + row;
    float c = O[n] * S[r] * U[n * 16 + r];
    C8[t] = c;
    w2b[n * 16 + r] = f2bf(c);
  }
  float nsq[8];
  for (int i = 0; i < 8; i++) nsq[i] = 0.f;
  for (int ch = 0; ch < 4; ch++){
    __syncthreads();                       // also guards C8 on first pass
    for (int j = 0; j < 16; j++){          // stage V[0:16][ch*1024 : +1024] fp32
      int idx4 = j * 256 + t;
      int r = idx4 >> 8, c4 = idx4 & 255;
      *(float4*)(Vl + r * 1024 + c4 * 4) =
          *(const float4*)(V + r * 4096 + ch * 1024 + c4 * 4);
    }
    __syncthreads();
    for (int row = 0; row < 8; row++){
      float4 b = *(const float4*)(bw + (n0 + row) * 4096 + ch * 1024 + t * 4);
      float a0 = 0.f, a1 = 0.f, a2 = 0.f, a3 = 0.f;
      for (int r = 0; r < 16; r++){
        float cr = C8[row * 16 + r];
        const float* vp = Vl + r * 1024 + t * 4;
        a0 += cr * vp[0]; a1 += cr * vp[1]; a2 += cr * vp[2]; a3 += cr * vp[3];
      }
      float d0 = b.x + a0, d1 = b.y + a1, d2 = b.z + a2, d3 = b.w + a3;
      nsq[row] += d0*d0 + d1*d1 + d2*d2 + d3*d3;
    }
  }
  for (int row = 0; row < 8; row++){
    float v = nsq[row];
    for (int off = 32; off > 0; off >>= 1) v += __shfl_down(v, off);
    if (lane == 0) red[row * 4 + wave] = v;
  }
  __syncthreads();
  if (t < 8){
    int n = n0 + t;
    float tot = red[t*4] + red[t*4+1] + red[t*4+2] + red[t*4+3];
    float s = mag[n] / sqrtf(tot);
    s_out[n] = s;
    sm1_out[n] = s - 1.0f;
  }
}

// ---------------- main GEMM + fused DoRA epilogue ----------------
// 128x128 tile, BK=64, 4 waves of 64x64, 16x16x32 bf16 MFMA.
// Staging via global_load_lds(16B). LDS layout = lane order; lane fetches
// xor-swizzled k-octet (ko = slot ^ (m&7)) so frag ds_read_b128 is 2-way max.
__global__ __launch_bounds__(256) void gemm_kernel(
    const unsigned short* __restrict__ A,   // x_bf16  [M][K]
    const unsigned short* __restrict__ B,   // w_bf16  [N][K]
    const unsigned short* __restrict__ Tb,  // t_bf16  [M][16]
    const unsigned short* __restrict__ W2b, // w2_bf16 [N][16]
    const float* __restrict__ s_arr, const float* __restrict__ sm1_arr,
    float* __restrict__ Cout){
  __shared__ unsigned short Al[128 * 64];   // 16KB
  __shared__ unsigned short Bl[128 * 64];   // 16KB
  int tid  = threadIdx.x;
  int lane = tid & 63;
  int wave = tid >> 6;
  int quad = lane >> 4;
  int r16  = lane & 15;
  int xm   = lane & 7;

  // supertile swizzle: 16 bm-blocks x all 32 bn per super -> x-chunk+W fit LLC
  const int GM = 16, NBN = 32;
  int bidx  = blockIdx.x;
  int super = bidx / (GM * NBN);
  int rem   = bidx % (GM * NBN);
  int bm = super * GM + (rem & (GM - 1));
  int bn = rem / GM;
  int m0 = bm * 128;
  int n0 = bn * 128;

  int wm = (wave >> 1) * 64;
  int wn = (wave & 1) * 64;

  int a_goff[4], b_goff[4], l_off[4];
  for (int j = 0; j < 4; j++){
    int u = j * 256 + tid;        // 16B-unit index; lds byte = u*16
    int mrow = u >> 3;
    int ko = (u & 7) ^ (mrow & 7);
    a_goff[j] = (m0 + mrow) * K_TOT + ko * 8;
    b_goff[j] = (n0 + mrow) * K_TOT + ko * 8;
    l_off[j]  = u * 8;            // in ushorts
  }
  int koff0 = (quad ^ xm) * 16;         // frag byte offset, k-step 0
  int koff1 = ((4 + quad) ^ xm) * 16;   // k-step 1

  f32x4 zf = {0.f, 0.f, 0.f, 0.f};
  f32x4 acc[4][4];
  for (int i = 0; i < 4; i++)
    for (int j = 0; j < 4; j++) acc[i][j] = zf;

  for (int kk = 0; kk < K_TOT; kk += 64){
    __syncthreads();
    for (int j = 0; j < 4; j++){
      async_lds16(A + a_goff[j] + kk, Al + l_off[j]);
      async_lds16(B + b_goff[j] + kk, Bl + l_off[j]);
    }
    __syncthreads();   // drains vmcnt -> LDS valid
    for (int ks = 0; ks < 2; ks++){
      int ko = ks ? koff1 : koff0;
      bf16x8 af[4], bfr[4];
      for (int tm = 0; tm < 4; tm++)
        af[tm] = *(const bf16x8*)((const char*)Al + (wm + tm*16 + r16) * 128 + ko);
      for (int tn = 0; tn < 4; tn++)
        bfr[tn] = *(const bf16x8*)((const char*)Bl + (wn + tn*16 + r16) * 128 + ko);
      for (int tm = 0; tm < 4; tm++)
        for (int tn = 0; tn < 4; tn++)
          acc[tm][tn] = __builtin_amdgcn_mfma_f32_16x16x32_bf16(
              af[tm], bfr[tn], acc[tm][tn], 0, 0, 0);
    }
  }

  // ---- epilogue: out = (s-1)*acc + s*(t @ W2^T) via zero-padded K=32 MFMA ----
  __syncthreads();   // all frag reads done before overwriting LDS
  {
    int row = tid >> 1, half = tid & 1;   // stage [128][16] bf16 + 16 zeros, row stride 40
    uint4 z = {0u, 0u, 0u, 0u};
    *(uint4*)(Al + row * 40 + half * 8)      = *(const uint4*)(Tb  + (m0 + row) * 16 + half * 8);
    *(uint4*)(Al + row * 40 + 16 + half * 8) = z;
    *(uint4*)(Bl + row * 40 + half * 8)      = *(const uint4*)(W2b + (n0 + row) * 16 + half * 8);
    *(uint4*)(Bl + row * 40 + 16 + half * 8) = z;
  }
  __syncthreads();
  for (int tn = 0; tn < 4; tn++){
    int nn = n0 + wn + tn * 16 + r16;
    float s   = s_arr[nn];
    float sm1 = sm1_arr[nn];
    bf16x8 b2 = *(const bf16x8*)(Bl + (wn + tn*16 + r16) * 40 + quad * 8);
    for (int tm = 0; tm < 4; tm++){
      bf16x8 a2 = *(const bf16x8*)(Al + (wm + tm*16 + r16) * 40 + quad * 8);
      f32x4 o2 = __builtin_amdgcn_mfma_f32_16x16x32_bf16(a2, b2, zf, 0, 0, 0);
      int mbase = m0 + wm + tm * 16 + quad * 4;
      float* cp = Cout + (long)mbase * N_TOT + nn;
      cp[0]         = sm1 * acc[tm][tn][0] + s * o2[0];
      cp[N_TOT]     = sm1 * acc[tm][tn][1] + s * o2[1];
      cp[2 * N_TOT] = sm1 * acc[tm][tn][2] + s * o2[2];
      cp[3 * N_TOT] = sm1 * acc[tm][tn][3] + s * o2[3];
    }
  }
}

extern "C" void kernel_launch(void* const* d_in, const int* in_sizes, int n_in,
                              void* d_out, int out_size, void* d_ws, size_t ws_size,
                              hipStream_t stream){
  const float* x   = (const float*)d_in[0];
  const float* U   = (const float*)d_in[1];
  const float* V   = (const float*)d_in[2];
  const float* S   = (const float*)d_in[3];
  const float* O   = (const float*)d_in[4];
  const float* mag = (const float*)d_in[5];
  const float* bw  = (const float*)d_in[6];
  float* out = (float*)d_out;

  char* ws = (char*)d_ws;
  unsigned short* xb  = (unsigned short*)(ws);               // 134217728 B
  unsigned short* wb  = (unsigned short*)(ws + 134217728);   //  33554432 B
  unsigned short* vb  = (unsigned short*)(ws + 167772160);   //    131072 B
  unsigned short* tb  = (unsigned short*)(ws + 167903232);   //    524288 B
  unsigned short* w2b = (unsigned short*)(ws + 168427520);   //    131072 B
  float* s_arr   = (float*)(ws + 168558592);                 //     16384 B
  float* sm1_arr = (float*)(ws + 168574976);                 //     16384 B
  (void)in_sizes; (void)n_in; (void)out_size; (void)ws_size;

  cast_f32_to_bf16_x4<<<16384, 256, 0, stream>>>(bw, wb, 4194304);
  cast_f32_to_bf16_x4<<<64,    256, 0, stream>>>(V,  vb, 16384);
  cast_f32_to_bf16_x4<<<65536, 256, 0, stream>>>(x,  xb, 16777216);
  tgemm_kernel<<<256, 256, 0, stream>>>(xb, vb, tb);
  norm_kernel<<<512, 256, 0, stream>>>(bw, U, S, O, mag, V, s_arr, sm1_arr, w2b);
  gemm_kernel<<<4096, 256, 0, stream>>>(xb, wb, tb, w2b, s_arr, sm1_arr, out);
}